// Round 9
// baseline (466.041 us; speedup 1.0000x reference)
//
#include <hip/hip_runtime.h>
#include <hip/hip_bf16.h>

#define VV 100000
#define EE 50
#define HH 64
#define BB 1024
#define TT 200
// 3H = 192

typedef float v4f __attribute__((ext_vector_type(4)));
typedef float f32x4 __attribute__((ext_vector_type(4)));
typedef short bf16x8 __attribute__((ext_vector_type(8)));

__device__ __forceinline__ float fsig(float x) {
    return 1.f / (1.f + __expf(-x));
}
__device__ __forceinline__ float ftanh(float x) {
    float e = __expf(2.f * x);
    return 1.f - 2.f / (e + 1.f);
}
// fp32 -> bf16 round-to-nearest-even (values are tame: no NaN/Inf handling needed)
__device__ __forceinline__ short f2bf(float f) {
    union { float f; unsigned u; } v; v.f = f;
    unsigned r = v.u + 0x7FFFu + ((v.u >> 16) & 1u);
    return (short)(r >> 16);
}

// ---------------- Kernel A: embW[v][c] = emb[v][:] @ Wx[:,c] + bi[c]  (both dirs via blockIdx.y) ----------------
__global__ __launch_bounds__(256) void embw_kernel(
    const float* __restrict__ emb,
    const float* __restrict__ Wx_f, const float* __restrict__ bi_f,
    const float* __restrict__ Wx_b, const float* __restrict__ bi_b,
    float* __restrict__ embW_f, float* __restrict__ embW_b)
{
    const float* Wx = blockIdx.y ? Wx_b : Wx_f;
    const float* bi = blockIdx.y ? bi_b : bi_f;
    float* embW     = blockIdx.y ? embW_b : embW_f;
    __shared__ float wx_lds[EE * 192];
    __shared__ float emb_lds[32 * EE];
    const int tid = threadIdx.x;
    const int v0 = blockIdx.x * 32;
    for (int i = tid; i < EE * 192; i += 256) wx_lds[i] = Wx[i];
    for (int i = tid; i < 32 * EE; i += 256) emb_lds[i] = emb[(size_t)v0 * EE + i];
    __syncthreads();
    const int cg = tid & 63;
    const int rg = tid >> 6;
    float acc[8][3];
    #pragma unroll
    for (int i = 0; i < 8; i++) {
        acc[i][0] = bi[cg];
        acc[i][1] = bi[cg + 64];
        acc[i][2] = bi[cg + 128];
    }
    for (int k = 0; k < EE; k++) {
        const float wx0 = wx_lds[k * 192 + cg];
        const float wx1 = wx_lds[k * 192 + cg + 64];
        const float wx2 = wx_lds[k * 192 + cg + 128];
        #pragma unroll
        for (int i = 0; i < 8; i++) {
            const float ev = emb_lds[(rg * 8 + i) * EE + k];
            acc[i][0] = fmaf(ev, wx0, acc[i][0]);
            acc[i][1] = fmaf(ev, wx1, acc[i][1]);
            acc[i][2] = fmaf(ev, wx2, acc[i][2]);
        }
    }
    #pragma unroll
    for (int i = 0; i < 8; i++) {
        const size_t row = (size_t)(v0 + rg * 8 + i) * 192;
        embW[row + cg]       = acc[i][0];
        embW[row + cg + 64]  = acc[i][1];
        embW[row + cg + 128] = acc[i][2];
    }
}

// ---------------- Kernel B v6: one wave per (2 sequences, direction); 1 wave/SIMD pinned ----
// R=2 rows share the 192 weight VGPRs -> all fixed per-step costs amortized 2x.
// Grid = 1024 one-wave blocks = exactly 1 wave per SIMD chip-wide; waves_per_eu(1,1)
// gives the RA the full single-wave register budget (512) with no occupancy incentive.
__global__ __launch_bounds__(64)
__attribute__((amdgpu_waves_per_eu(1, 1)))
void gru6_kernel(
    const int* __restrict__ ids,
    const float* __restrict__ embW_f, const float* __restrict__ embW_b,
    const float* __restrict__ Wh_f, const float* __restrict__ br_f,
    const float* __restrict__ Wh_b, const float* __restrict__ br_b,
    float* __restrict__ outb,     // [B, T, 128]
    float* __restrict__ hf_out)   // [B, 64]
{
    const int j   = threadIdx.x;
    const int b0  = blockIdx.x * 2;
    const int dir = blockIdx.y;
    const float* eW = dir ? embW_b : embW_f;
    const float* Wh = dir ? Wh_b : Wh_f;
    const float* br = dir ? br_b : br_f;

    v4f wz4[16], wr4[16], wn4[16];
    #pragma unroll
    for (int k4 = 0; k4 < 16; k4++) {
        wz4[k4][0] = Wh[(4 * k4 + 0) * 192 + j];
        wz4[k4][1] = Wh[(4 * k4 + 1) * 192 + j];
        wz4[k4][2] = Wh[(4 * k4 + 2) * 192 + j];
        wz4[k4][3] = Wh[(4 * k4 + 3) * 192 + j];
        wr4[k4][0] = Wh[(4 * k4 + 0) * 192 + 64 + j];
        wr4[k4][1] = Wh[(4 * k4 + 1) * 192 + 64 + j];
        wr4[k4][2] = Wh[(4 * k4 + 2) * 192 + 64 + j];
        wr4[k4][3] = Wh[(4 * k4 + 3) * 192 + 64 + j];
        wn4[k4][0] = Wh[(4 * k4 + 0) * 192 + 128 + j];
        wn4[k4][1] = Wh[(4 * k4 + 1) * 192 + 128 + j];
        wn4[k4][2] = Wh[(4 * k4 + 2) * 192 + 128 + j];
        wn4[k4][3] = Wh[(4 * k4 + 3) * 192 + 128 + j];
    }
    const float brz = br[j], brr = br[64 + j], brn = br[128 + j];

    __shared__ __align__(16) float h_lds[2][64];
    __shared__ int ids_lds[2 * TT];
    for (int i = j; i < 2 * TT; i += 64) ids_lds[i] = ids[(size_t)b0 * TT + i];
    h_lds[0][j] = 0.f;
    h_lds[1][j] = 0.f;
    float hj0 = 0.f, hj1 = 0.f;
    __syncthreads();   // one-time; none inside the step loop

    const int t0 = dir ? (TT - 1) : 0;
    const int dt = dir ? -1 : 1;

    int   idA0 = ids_lds[t0];
    int   idB0 = ids_lds[TT + t0];
    float gzA0 = eW[(size_t)idA0 * 192 + j];
    float grA0 = eW[(size_t)idA0 * 192 + 64 + j];
    float gnA0 = eW[(size_t)idA0 * 192 + 128 + j];
    float gzB0 = eW[(size_t)idB0 * 192 + j];
    float grB0 = eW[(size_t)idB0 * 192 + 64 + j];
    float gnB0 = eW[(size_t)idB0 * 192 + 128 + j];
    int   idA1 = ids_lds[t0 + dt];
    int   idB1 = ids_lds[TT + t0 + dt];
    float gzA1 = eW[(size_t)idA1 * 192 + j];
    float grA1 = eW[(size_t)idA1 * 192 + 64 + j];
    float gnA1 = eW[(size_t)idA1 * 192 + 128 + j];
    float gzB1 = eW[(size_t)idB1 * 192 + j];
    float grB1 = eW[(size_t)idB1 * 192 + 64 + j];
    float gnB1 = eW[(size_t)idB1 * 192 + 128 + j];

    float* obaseA = outb + (size_t)b0 * TT * 128 + dir * 64 + j;
    float* obaseB = obaseA + (size_t)TT * 128;

    for (int s = 0; s < TT; s++) {
        const int t = t0 + s * dt;
        // prefetch step s+2 (both rows)
        int idA2 = 0, idB2 = 0;
        float gzA2 = 0.f, grA2 = 0.f, gnA2 = 0.f, gzB2 = 0.f, grB2 = 0.f, gnB2 = 0.f;
        if (s + 2 < TT) {
            idA2 = ids_lds[t + 2 * dt];
            idB2 = ids_lds[TT + t + 2 * dt];
            gzA2 = eW[(size_t)idA2 * 192 + j];
            grA2 = eW[(size_t)idA2 * 192 + 64 + j];
            gnA2 = eW[(size_t)idA2 * 192 + 128 + j];
            gzB2 = eW[(size_t)idB2 * 192 + j];
            grB2 = eW[(size_t)idB2 * 192 + 64 + j];
            gnB2 = eW[(size_t)idB2 * 192 + 128 + j];
        }
        v4f aZ0 = {brz, 0.f, 0.f, 0.f};
        v4f aR0 = {brr, 0.f, 0.f, 0.f};
        v4f aN0 = {brn, 0.f, 0.f, 0.f};
        v4f aZ1 = {brz, 0.f, 0.f, 0.f};
        v4f aR1 = {brr, 0.f, 0.f, 0.f};
        v4f aN1 = {brn, 0.f, 0.f, 0.f};
        const v4f* h40 = (const v4f*)&h_lds[0][0];
        const v4f* h41 = (const v4f*)&h_lds[1][0];
        #pragma unroll
        for (int k4 = 0; k4 < 16; k4++) {
            const v4f hv0 = h40[k4];
            const v4f hv1 = h41[k4];
            aZ0 = __builtin_elementwise_fma(hv0, wz4[k4], aZ0);
            aR0 = __builtin_elementwise_fma(hv0, wr4[k4], aR0);
            aN0 = __builtin_elementwise_fma(hv0, wn4[k4], aN0);
            aZ1 = __builtin_elementwise_fma(hv1, wz4[k4], aZ1);
            aR1 = __builtin_elementwise_fma(hv1, wr4[k4], aR1);
            aN1 = __builtin_elementwise_fma(hv1, wn4[k4], aN1);
        }
        {
            const float az = (aZ0[0] + aZ0[1]) + (aZ0[2] + aZ0[3]);
            const float ar = (aR0[0] + aR0[1]) + (aR0[2] + aR0[3]);
            const float an = (aN0[0] + aN0[1]) + (aN0[2] + aN0[3]);
            const float z  = fsig(gzA0 + az);
            const float r  = fsig(grA0 + ar);
            const float hh = ftanh(gnA0 + r * an);
            float hnew = z * hj0 + (1.f - z) * hh;
            hnew = (idA0 != 0) ? hnew : hj0;
            hj0 = hnew;
            h_lds[0][j] = hj0;
            obaseA[(size_t)t * 128] = hj0;
        }
        {
            const float az = (aZ1[0] + aZ1[1]) + (aZ1[2] + aZ1[3]);
            const float ar = (aR1[0] + aR1[1]) + (aR1[2] + aR1[3]);
            const float an = (aN1[0] + aN1[1]) + (aN1[2] + aN1[3]);
            const float z  = fsig(gzB0 + az);
            const float r  = fsig(grB0 + ar);
            const float hh = ftanh(gnB0 + r * an);
            float hnew = z * hj1 + (1.f - z) * hh;
            hnew = (idB0 != 0) ? hnew : hj1;
            hj1 = hnew;
            h_lds[1][j] = hj1;
            obaseB[(size_t)t * 128] = hj1;
        }
        idA0 = idA1; gzA0 = gzA1; grA0 = grA1; gnA0 = gnA1;
        idB0 = idB1; gzB0 = gzB1; grB0 = grB1; gnB0 = gnB1;
        idA1 = idA2; gzA1 = gzA2; grA1 = grA2; gnA1 = gnA2;
        idB1 = idB2; gzB1 = gzB2; grB1 = grB2; gnB1 = gnB2;
    }
    if (dir == 0) {
        hf_out[(size_t)b0 * 64 + j] = hj0;
        hf_out[(size_t)(b0 + 1) * 64 + j] = hj1;
    }
}

// ---------------- Kernel C v7: MFMA keys GEMM ----------------
// One block per b, 256 thr = 4 waves. keys[t, c] = out[b,t,:128] @ Wk[:, c].
// mfma_f32_16x16x32_bf16: A row = lane&15 (=t within tile), k = 8*(lane>>4)+j;
// B col = lane&15 (=c within n-tile), same k map; C/D col=lane&15, row=4*(lane>>4)+reg (m89-verified).
// Wk staged once into LDS, pre-swizzled to B-fragment order -> one ds_read_b128 per MFMA.
#define NTILE 13   // ceil(200/16)

__global__ __launch_bounds__(256) void attn7_kernel(
    const int* __restrict__ ids,
    const float* __restrict__ outb,   // [B,T,128] fp32
    const float* __restrict__ hf,     // [B,64]
    const float* __restrict__ Wk, const float* __restrict__ bk,
    const float* __restrict__ Wq, const float* __restrict__ bq,
    const float* __restrict__ We, const float* __restrict__ be,
    float* __restrict__ ctx)          // [B,128]
{
    __shared__ __align__(16) short wk_sw[1024 * 8];  // [slot][j]; slot = ks*256 + lhi*64 + nt*16 + l15
    __shared__ float q_lds[64];
    __shared__ float we_lds[64];
    __shared__ float e_lds[TT];
    __shared__ float part[4][128];
    const int b = blockIdx.x;
    const int tid = threadIdx.x;
    const int w = tid >> 6;
    const int lane = tid & 63;
    const int l15 = lane & 15;
    const int lhi = lane >> 4;

    // Stage Wk (fp32 -> bf16) into fragment-ordered LDS. Each thread fills 4 slots of 8 values.
    #pragma unroll
    for (int i = 0; i < 4; i++) {
        const int slot = tid + 256 * i;
        const int s_l15 = slot & 15;
        const int s_nt  = (slot >> 4) & 3;
        const int s_lhi = (slot >> 6) & 3;
        const int s_ks  = slot >> 8;
        const int kbase = 32 * s_ks + 8 * s_lhi;
        const int col   = 16 * s_nt + s_l15;
        bf16x8 v;
        #pragma unroll
        for (int jj = 0; jj < 8; jj++) v[jj] = f2bf(Wk[(size_t)(kbase + jj) * 64 + col]);
        *(bf16x8*)&wk_sw[slot * 8] = v;
    }
    // q[c] = bq[c] + hf[b] @ Wq[:,c] (wave 0; coalesced column reads)
    if (tid < 64) {
        float qc = bq[tid];
        const float* hfb = hf + (size_t)b * 64;
        for (int k = 0; k < 64; k++) qc = fmaf(hfb[k], Wq[k * 64 + tid], qc);
        q_lds[tid] = qc;
        we_lds[tid] = We[tid];
    }
    __syncthreads();

    // keys + energy, 16-row tiles round-robined over the 4 waves
    for (int tile = w; tile < NTILE; tile += 4) {
        const int t0 = tile * 16;
        const int t = t0 + l15;
        f32x4 acc[4];
        #pragma unroll
        for (int nt = 0; nt < 4; nt++) { acc[nt][0] = 0.f; acc[nt][1] = 0.f; acc[nt][2] = 0.f; acc[nt][3] = 0.f; }
        #pragma unroll
        for (int ks = 0; ks < 4; ks++) {
            bf16x8 a;
            if (t < TT) {
                const float* p = outb + ((size_t)b * TT + t) * 128 + 32 * ks + 8 * lhi;
                const float4 lo = *(const float4*)p;
                const float4 hi = *(const float4*)(p + 4);
                a[0] = f2bf(lo.x); a[1] = f2bf(lo.y); a[2] = f2bf(lo.z); a[3] = f2bf(lo.w);
                a[4] = f2bf(hi.x); a[5] = f2bf(hi.y); a[6] = f2bf(hi.z); a[7] = f2bf(hi.w);
            } else {
                #pragma unroll
                for (int jj = 0; jj < 8; jj++) a[jj] = 0;
            }
            #pragma unroll
            for (int nt = 0; nt < 4; nt++) {
                const bf16x8 bf = *(const bf16x8*)&wk_sw[(ks * 256 + lhi * 64 + nt * 16 + l15) * 8];
                acc[nt] = __builtin_amdgcn_mfma_f32_16x16x32_bf16(a, bf, acc[nt], 0, 0, 0);
            }
        }
        // energy partials: ep[r] = sum_c We[c] * tanh(keys[t0+4*lhi+r][c] + q[c]); c spread over l15 x nt
        float ep0 = 0.f, ep1 = 0.f, ep2 = 0.f, ep3 = 0.f;
        #pragma unroll
        for (int nt = 0; nt < 4; nt++) {
            const int c = 16 * nt + l15;
            const float qn = q_lds[c];
            const float wen = we_lds[c];
            ep0 = fmaf(wen, ftanh(acc[nt][0] + qn), ep0);
            ep1 = fmaf(wen, ftanh(acc[nt][1] + qn), ep1);
            ep2 = fmaf(wen, ftanh(acc[nt][2] + qn), ep2);
            ep3 = fmaf(wen, ftanh(acc[nt][3] + qn), ep3);
        }
        #pragma unroll
        for (int off = 1; off < 16; off <<= 1) {
            ep0 += __shfl_xor(ep0, off);
            ep1 += __shfl_xor(ep1, off);
            ep2 += __shfl_xor(ep2, off);
            ep3 += __shfl_xor(ep3, off);
        }
        if (l15 == 0) {
            const int rbase = t0 + 4 * lhi;
            if (rbase + 0 < TT) e_lds[rbase + 0] = ep0;
            if (rbase + 1 < TT) e_lds[rbase + 1] = ep1;
            if (rbase + 2 < TT) e_lds[rbase + 2] = ep2;
            if (rbase + 3 < TT) e_lds[rbase + 3] = ep3;
        }
    }
    __syncthreads();
    // softmax over t (wave 0)
    if (w == 0) {
        const float bev = be[0];
        for (int t = lane; t < TT; t += 64) {
            float e = e_lds[t] + bev;
            if (ids[(size_t)b * TT + t] == 0) e -= 1e9f;
            e_lds[t] = e;
        }
        float m = -1e30f;
        for (int t = lane; t < TT; t += 64) m = fmaxf(m, e_lds[t]);
        #pragma unroll
        for (int off = 32; off > 0; off >>= 1) m = fmaxf(m, __shfl_xor(m, off));
        float ssum = 0.f;
        for (int t = lane; t < TT; t += 64) { const float v = __expf(e_lds[t] - m); e_lds[t] = v; ssum += v; }
        #pragma unroll
        for (int off = 32; off > 0; off >>= 1) ssum += __shfl_xor(ssum, off);
        const float inv = 1.f / ssum;
        for (int t = lane; t < TT; t += 64) e_lds[t] *= inv;
    }
    __syncthreads();
    // context (fp32): wave w covers t ≡ w (mod 4)
    float c0 = 0.f, c1 = 0.f;
    for (int t = w; t < TT; t += 4) {
        const float* orow = outb + ((size_t)b * TT + t) * 128;
        const float wt = e_lds[t];
        c0 = fmaf(wt, orow[lane], c0);
        c1 = fmaf(wt, orow[64 + lane], c1);
    }
    part[w][lane] = c0;
    part[w][64 + lane] = c1;
    __syncthreads();
    if (tid < 128)
        ctx[(size_t)b * 128 + tid] = part[0][tid] + part[1][tid] + part[2][tid] + part[3][tid];
}

// ---------------- (fallback) GRU 3-wave kernel, recompute-gx variant ----------------
template<bool USE_EMBW>
__global__ __launch_bounds__(192, 2) void gru_kernel(
    const int* __restrict__ ids,
    const float* __restrict__ embW_f, const float* __restrict__ embW_b,
    const float* __restrict__ emb,
    const float* __restrict__ Wx_f, const float* __restrict__ bi_f,
    const float* __restrict__ Wx_b, const float* __restrict__ bi_b,
    const float* __restrict__ Wh_f, const float* __restrict__ br_f,
    const float* __restrict__ Wh_b, const float* __restrict__ br_b,
    float* __restrict__ outb, float* __restrict__ hf_out)
{
    constexpr int R = 4;
    __shared__ float h_lds[R][64];
    __shared__ float rg_lds[R][64];
    __shared__ float hh_lds[R][64];
    __shared__ int ids_lds[R * TT];
    const int tid = threadIdx.x;
    const int w = tid >> 6;
    const int j = tid & 63;
    const int dir = blockIdx.y;
    const int b0 = blockIdx.x * R;
    const float* embW = dir ? embW_b : embW_f;
    const float* Wh   = dir ? Wh_b : Wh_f;
    const float* br   = dir ? br_b : br_f;
    const float* Wx   = dir ? Wx_b : Wx_f;
    const float* bi   = dir ? bi_b : bi_f;
    const int c = w * 64 + j;

    float whc[64];
    #pragma unroll
    for (int k = 0; k < 64; k++) whc[k] = Wh[k * 192 + c];
    const float brc = br[c];
    float wxc[EE];
    float bic = 0.f;
    if (!USE_EMBW) {
        #pragma unroll
        for (int k = 0; k < EE; k++) wxc[k] = Wx[k * 192 + c];
        bic = bi[c];
    }
    for (int i = tid; i < R * TT; i += 192) ids_lds[i] = ids[(size_t)b0 * TT + i];
    if (w == 0) {
        #pragma unroll
        for (int r = 0; r < R; r++) h_lds[r][j] = 0.f;
    }
    __syncthreads();

    for (int s = 0; s < TT; s++) {
        const int t = dir ? (TT - 1 - s) : s;
        int idv[R];
        float gxv[R], accv[R];
        #pragma unroll
        for (int r = 0; r < R; r++) idv[r] = ids_lds[r * TT + t];
        if (USE_EMBW) {
            #pragma unroll
            for (int r = 0; r < R; r++) gxv[r] = embW[(size_t)idv[r] * 192 + c];
        } else {
            #pragma unroll
            for (int r = 0; r < R; r++) {
                float acc = bic;
                const float* er = emb + (size_t)idv[r] * EE;
                #pragma unroll
                for (int k = 0; k < EE; k++) acc = fmaf(er[k], wxc[k], acc);
                gxv[r] = acc;
            }
        }
        #pragma unroll
        for (int r = 0; r < R; r++) {
            float acc = brc;
            const float4* h4 = (const float4*)(&h_lds[r][0]);
            #pragma unroll
            for (int k4 = 0; k4 < 16; k4++) {
                const float4 hv = h4[k4];
                acc = fmaf(hv.x, whc[4 * k4 + 0], acc);
                acc = fmaf(hv.y, whc[4 * k4 + 1], acc);
                acc = fmaf(hv.z, whc[4 * k4 + 2], acc);
                acc = fmaf(hv.w, whc[4 * k4 + 3], acc);
            }
            accv[r] = acc;
        }
        float zg[R] = {};
        if (w == 1) {
            #pragma unroll
            for (int r = 0; r < R; r++) rg_lds[r][j] = fsig(gxv[r] + accv[r]);
        } else if (w == 0) {
            #pragma unroll
            for (int r = 0; r < R; r++) zg[r] = fsig(gxv[r] + accv[r]);
        }
        __syncthreads();
        if (w == 2) {
            #pragma unroll
            for (int r = 0; r < R; r++)
                hh_lds[r][j] = ftanh(gxv[r] + rg_lds[r][j] * accv[r]);
        }
        __syncthreads();
        if (w == 0) {
            #pragma unroll
            for (int r = 0; r < R; r++) {
                const float hold = h_lds[r][j];
                float hnew = hold;
                if (idv[r] != 0) {
                    const float hh = hh_lds[r][j];
                    hnew = zg[r] * hold + (1.f - zg[r]) * hh;
                }
                h_lds[r][j] = hnew;
                outb[((size_t)(b0 + r) * TT + t) * 128 + dir * 64 + j] = hnew;
            }
        }
        __syncthreads();
    }
    if (dir == 0 && w == 0) {
        #pragma unroll
        for (int r = 0; r < R; r++) hf_out[(size_t)(b0 + r) * 64 + j] = h_lds[r][j];
    }
}

extern "C" void kernel_launch(void* const* d_in, const int* in_sizes, int n_in,
                              void* d_out, int out_size, void* d_ws, size_t ws_size,
                              hipStream_t stream) {
    const int*   ids  = (const int*)d_in[0];
    const float* emb  = (const float*)d_in[1];
    const float* Wx_f = (const float*)d_in[2];
    const float* Wh_f = (const float*)d_in[3];
    const float* bi_f = (const float*)d_in[4];
    const float* br_f = (const float*)d_in[5];
    const float* Wx_b = (const float*)d_in[6];
    const float* Wh_b = (const float*)d_in[7];
    const float* bi_b = (const float*)d_in[8];
    const float* br_b = (const float*)d_in[9];
    const float* Wk   = (const float*)d_in[10];
    const float* bk   = (const float*)d_in[11];
    const float* Wq   = (const float*)d_in[12];
    const float* bq   = (const float*)d_in[13];
    const float* We   = (const float*)d_in[14];
    const float* be   = (const float*)d_in[15];
    float* ctx = (float*)d_out;

    float* ws = (float*)d_ws;
    const size_t embw_elems = (size_t)VV * 192;
    const size_t out_elems  = (size_t)BB * TT * 128;
    const size_t hf_elems   = (size_t)BB * 64;
    const size_t need_embw  = (2 * embw_elems + out_elems + hf_elems) * sizeof(float);
    const bool use_embw = (ws_size >= need_embw);

    float *embW_f = nullptr, *embW_b = nullptr, *outb, *hf;
    if (use_embw) {
        embW_f = ws;
        embW_b = embW_f + embw_elems;
        outb   = embW_b + embw_elems;
        hf     = outb + out_elems;
    } else {
        outb = ws;
        hf   = outb + out_elems;
    }

    if (use_embw) {
        embw_kernel<<<dim3(VV / 32, 2), 256, 0, stream>>>(
            emb, Wx_f, bi_f, Wx_b, bi_b, embW_f, embW_b);
        gru6_kernel<<<dim3(BB / 2, 2), 64, 0, stream>>>(
            ids, embW_f, embW_b, Wh_f, br_f, Wh_b, br_b, outb, hf);
    } else {
        gru_kernel<false><<<dim3(BB / 4, 2), 192, 0, stream>>>(
            ids, embW_f, embW_b, emb, Wx_f, bi_f, Wx_b, bi_b,
            Wh_f, br_f, Wh_b, br_b, outb, hf);
    }
    attn7_kernel<<<BB, 256, 0, stream>>>(ids, outb, hf, Wk, bk, Wq, bq, We, be, ctx);
}